// Round 13
// baseline (1019.385 us; speedup 1.0000x reference)
//
#include <hip/hip_runtime.h>
#include <hip/hip_bf16.h>
#include <math.h>

// R13: conv2t = 4x8ci passes + register prefetch pipeline (hide HBM latency
// behind compute; FMA chain per output still ci->kh->kw = bit-exact).
// Decoder intermediates d3/d4/d5 now bf16 (halves traffic; dect stages bf16
// natively). dect tiles split 16x16 -> 8x16 (LDS 25.9KB, 6 blk/CU).

__device__ __forceinline__ int rfl(int v) { return __builtin_amdgcn_readfirstlane(v); }

typedef __attribute__((ext_vector_type(8))) short s8v;
typedef __attribute__((ext_vector_type(4))) float f4v;

__device__ __forceinline__ ushort f2bf(float f) {
    __hip_bfloat16 h = __float2bfloat16(f);
    return *(ushort*)&h;
}
__device__ __forceinline__ float bf2f(ushort u) {
    return __uint_as_float(((unsigned int)u) << 16);
}

// -------- K1: conv 4x4 s2 p1, 3->32. Tile: 4 oh x 8 co per thread. (bit-exact)
__global__ __launch_bounds__(256) void k_conv1(const float* __restrict__ x, const float* __restrict__ w,
                                               const float* __restrict__ bias, float* __restrict__ out) {
    int t = blockIdx.x * 256 + threadIdx.x;
    int ow  = t & 127;
    int oh0 = ((t >> 7) & 31) * 4;
    int co0 = rfl((t >> 12) & 3) * 8;
    int b   = rfl(t >> 14);
    float acc[4][8] = {};
    for (int ci = 0; ci < 3; ci++) {
        const float* xp = x + (b * 3 + ci) * 65536;
        const float* wp = w + (co0 * 3 + ci) * 16;      // co stride 48
        #pragma unroll
        for (int r = 0; r < 10; r++) {
            int ih = oh0 * 2 - 1 + r;
            bool rok = (ih >= 0) && (ih < 256);
            int ihc = rok ? ih : 0;
            float v[4];
            #pragma unroll
            for (int c = 0; c < 4; c++) {
                int iw = ow * 2 - 1 + c;
                bool ok = rok && (iw >= 0) && (iw < 256);
                int iwc = iw < 0 ? 0 : (iw > 255 ? 255 : iw);
                float vv = xp[ihc * 256 + iwc];
                v[c] = ok ? vv : 0.f;
            }
            #pragma unroll
            for (int o = 0; o < 4; o++) {
                int kh = r - 2 * o;
                if (kh >= 0 && kh < 4) {
                    #pragma unroll
                    for (int cc = 0; cc < 8; cc++) {
                        const float* wc = wp + cc * 48 + kh * 4;
                        acc[o][cc] = __builtin_fmaf(v[0], wc[0], acc[o][cc]);
                        acc[o][cc] = __builtin_fmaf(v[1], wc[1], acc[o][cc]);
                        acc[o][cc] = __builtin_fmaf(v[2], wc[2], acc[o][cc]);
                        acc[o][cc] = __builtin_fmaf(v[3], wc[3], acc[o][cc]);
                    }
                }
            }
        }
    }
    #pragma unroll
    for (int cc = 0; cc < 8; cc++) {
        float bv = bias[co0 + cc];
        #pragma unroll
        for (int o = 0; o < 4; o++) {
            float v = acc[o][cc] + bv;
            out[((b * 32 + co0 + cc) * 128 + oh0 + o) * 128 + ow] = v > 0.f ? v : 0.f;
        }
    }
}

// -------- K2: conv 4x4 s2 p1, 32->64. 4x8ci passes, register-prefetch pipeline.
__global__ __launch_bounds__(256) void k_conv2t(const float* __restrict__ h1, const float* __restrict__ w,
                                                const float* __restrict__ bias, float* __restrict__ out) {
    __shared__ float P[8][18][2][10];   // 11,520 B -> ~8 blocks/CU
    int bx = blockIdx.x;
    int b  = bx >> 6;
    int ty = (bx >> 3) & 7, tx = bx & 7;
    int oh0 = ty * 8, ow0 = tx * 8;
    int tid = threadIdx.x;
    int lane = tid & 63;
    int dy = lane >> 3, dx = lane & 7;
    int co_base = rfl(tid >> 6) * 16;
    int oh = oh0 + dy, ow = ow0 + dx;
    float s00 = 0.f, s01 = 0.f, s02 = 0.f, s03 = 0.f;
    float s10 = 0.f, s11 = 0.f, s12 = 0.f, s13 = 0.f;
    float s20 = 0.f, s21 = 0.f, s22 = 0.f, s23 = 0.f;
    float s30 = 0.f, s31 = 0.f, s32 = 0.f, s33 = 0.f;
    float pf[11];
    // prefetch pass 0 (8 ci x 18 x 18 = 2592 elements)
    #pragma unroll
    for (int k = 0; k < 11; k++) {
        int i = tid + (k << 8);
        float v = 0.f;
        if (i < 2592) {
            int cl = i / 324, rem = i - cl * 324;
            int r = rem / 18, c = rem - r * 18;
            int ih = oh0 * 2 - 1 + r, iw = ow0 * 2 - 1 + c;
            if (ih >= 0 && ih < 128 && iw >= 0 && iw < 128)
                v = h1[(b * 32 + cl) * 16384 + ih * 128 + iw];
        }
        pf[k] = v;
    }
    for (int pass = 0; pass < 4; pass++) {
        __syncthreads();
        #pragma unroll
        for (int k = 0; k < 11; k++) {     // registers -> LDS
            int i = tid + (k << 8);
            if (i < 2592) {
                int cl = i / 324, rem = i - cl * 324;
                int r = rem / 18, c = rem - r * 18;
                P[cl][r][c & 1][c >> 1] = pf[k];
            }
        }
        __syncthreads();
        if (pass < 3) {                    // prefetch next pass; overlaps compute below
            int cib = (pass + 1) * 8;
            #pragma unroll
            for (int k = 0; k < 11; k++) {
                int i = tid + (k << 8);
                float v = 0.f;
                if (i < 2592) {
                    int cl = i / 324, rem = i - cl * 324;
                    int r = rem / 18, c = rem - r * 18;
                    int ih = oh0 * 2 - 1 + r, iw = ow0 * 2 - 1 + c;
                    if (ih >= 0 && ih < 128 && iw >= 0 && iw < 128)
                        v = h1[(b * 32 + cib + cl) * 16384 + ih * 128 + iw];
                }
                pf[k] = v;
            }
        }
        int cib = pass * 8;
        #pragma unroll
        for (int cc = 0; cc < 4; cc++) {
            int co0 = co_base + cc * 4;
            float a0 = (cc == 0) ? s00 : (cc == 1) ? s10 : (cc == 2) ? s20 : s30;
            float a1 = (cc == 0) ? s01 : (cc == 1) ? s11 : (cc == 2) ? s21 : s31;
            float a2 = (cc == 0) ? s02 : (cc == 1) ? s12 : (cc == 2) ? s22 : s32;
            float a3 = (cc == 0) ? s03 : (cc == 1) ? s13 : (cc == 2) ? s23 : s33;
            for (int cl = 0; cl < 8; cl++) {
                const float* wp0 = w + ((co0 + 0) * 32 + cib + cl) * 16;
                const float* wp1 = w + ((co0 + 1) * 32 + cib + cl) * 16;
                const float* wp2 = w + ((co0 + 2) * 32 + cib + cl) * 16;
                const float* wp3 = w + ((co0 + 3) * 32 + cib + cl) * 16;
                #pragma unroll
                for (int kh = 0; kh < 4; kh++) {
                    int r = 2 * dy + kh;
                    float v0 = P[cl][r][0][dx];
                    float v1 = P[cl][r][1][dx];
                    float v2 = P[cl][r][0][dx + 1];
                    float v3 = P[cl][r][1][dx + 1];
                    a0 = __builtin_fmaf(v0, wp0[kh*4+0], a0); a0 = __builtin_fmaf(v1, wp0[kh*4+1], a0);
                    a0 = __builtin_fmaf(v2, wp0[kh*4+2], a0); a0 = __builtin_fmaf(v3, wp0[kh*4+3], a0);
                    a1 = __builtin_fmaf(v0, wp1[kh*4+0], a1); a1 = __builtin_fmaf(v1, wp1[kh*4+1], a1);
                    a1 = __builtin_fmaf(v2, wp1[kh*4+2], a1); a1 = __builtin_fmaf(v3, wp1[kh*4+3], a1);
                    a2 = __builtin_fmaf(v0, wp2[kh*4+0], a2); a2 = __builtin_fmaf(v1, wp2[kh*4+1], a2);
                    a2 = __builtin_fmaf(v2, wp2[kh*4+2], a2); a2 = __builtin_fmaf(v3, wp2[kh*4+3], a2);
                    a3 = __builtin_fmaf(v0, wp3[kh*4+0], a3); a3 = __builtin_fmaf(v1, wp3[kh*4+1], a3);
                    a3 = __builtin_fmaf(v2, wp3[kh*4+2], a3); a3 = __builtin_fmaf(v3, wp3[kh*4+3], a3);
                }
            }
            if (cc == 0)      { s00 = a0; s01 = a1; s02 = a2; s03 = a3; }
            else if (cc == 1) { s10 = a0; s11 = a1; s12 = a2; s13 = a3; }
            else if (cc == 2) { s20 = a0; s21 = a1; s22 = a2; s23 = a3; }
            else              { s30 = a0; s31 = a1; s32 = a2; s33 = a3; }
        }
    }
    float r0, r1, r2, r3;
    #pragma unroll
    for (int cc = 0; cc < 4; cc++) {
        int co0 = co_base + cc * 4;
        if (cc == 0)      { r0 = s00; r1 = s01; r2 = s02; r3 = s03; }
        else if (cc == 1) { r0 = s10; r1 = s11; r2 = s12; r3 = s13; }
        else if (cc == 2) { r0 = s20; r1 = s21; r2 = s22; r3 = s23; }
        else              { r0 = s30; r1 = s31; r2 = s32; r3 = s33; }
        float v0 = r0 + bias[co0 + 0], v1 = r1 + bias[co0 + 1];
        float v2 = r2 + bias[co0 + 2], v3 = r3 + bias[co0 + 3];
        out[((b * 64 + co0 + 0) * 64 + oh) * 64 + ow] = v0 > 0.f ? v0 : 0.f;
        out[((b * 64 + co0 + 1) * 64 + oh) * 64 + ow] = v1 > 0.f ? v1 : 0.f;
        out[((b * 64 + co0 + 2) * 64 + oh) * 64 + ow] = v2 > 0.f ? v2 : 0.f;
        out[((b * 64 + co0 + 3) * 64 + oh) * 64 + ow] = v3 > 0.f ? v3 : 0.f;
    }
}

// -------- K3: conv 1x1, 64->8 (bit-exact, unchanged).
__global__ __launch_bounds__(256) void k_conv3(const float* __restrict__ h2, const float* __restrict__ w,
                                               const float* __restrict__ bias, float* __restrict__ zf) {
    __shared__ float wl[8][64];
    __shared__ float bl[8];
    int tid = threadIdx.x;
    for (int i = tid; i < 512; i += 256) wl[i >> 6][i & 63] = w[i];
    if (tid < 8) bl[tid] = bias[tid];
    __syncthreads();
    int t = blockIdx.x * 256 + tid;
    int b = t >> 12, hw = t & 4095;
    float acc[8];
    for (int d = 0; d < 8; d++) acc[d] = 0.f;
    for (int ci = 0; ci < 64; ci++) {
        float v = h2[(b * 64 + ci) * 4096 + hw];
        for (int d = 0; d < 8; d++) acc[d] = __builtin_fmaf(v, wl[d][ci], acc[d]);
    }
    for (int d = 0; d < 8; d++)
        zf[(b * 8 + d) * 4096 + hw] = acc[d] + bl[d];
}

// -------- K4: VQ argmin (bit-exact, unchanged).
__global__ __launch_bounds__(256) void k_vq(const float* __restrict__ zf, const float* __restrict__ cb,
                                            int* __restrict__ idx, float* __restrict__ out_idx) {
    __shared__ float cbs[512][8];
    __shared__ float c2s[512];
    int tid = threadIdx.x;
    for (int i = tid; i < 4096; i += 256) cbs[i >> 3][i & 7] = cb[i];
    __syncthreads();
    for (int k = tid; k < 512; k += 256) {
        float s = 0.f;
        for (int d = 0; d < 8; d++) {
            float c = cbs[k][d];
            s = s + __fmul_rn(c, c);
        }
        c2s[k] = s;
    }
    __syncthreads();
    int n = blockIdx.x * 256 + tid;
    int b = n >> 12, hw = n & 4095;
    float zv[8], s1 = 0.f;
    for (int d = 0; d < 8; d++) {
        float z = zf[(b * 8 + d) * 4096 + hw];
        zv[d] = z;
        s1 = s1 + __fmul_rn(z, z);
    }
    float best = 3.4e38f; int bi = 0;
    for (int k = 0; k < 512; k++) {
        float dot = 0.f;
        for (int d = 0; d < 8; d++) dot = __builtin_fmaf(zv[d], cbs[k][d], dot);
        float a = s1 + c2s[k];
        float dist = a - __fmul_rn(2.0f, dot);
        if (dist < best) { best = dist; bi = k; }
    }
    idx[n] = bi;
    out_idx[n] = (float)bi;
}

// -------- K5: z_q + loss partials (unchanged).
__global__ __launch_bounds__(256) void k_zq(const int* __restrict__ idx, const float* __restrict__ cb,
                                            const float* __restrict__ zf, float* __restrict__ zq,
                                            double* __restrict__ partial) {
    __shared__ double red[256];
    int t = blockIdx.x * 256 + threadIdx.x;
    float q = cb[idx[t >> 3] * 8 + (t & 7)];
    zq[t] = q;
    double d = (double)zf[t] - (double)q;
    red[threadIdx.x] = d * d;
    __syncthreads();
    for (int s = 128; s > 0; s >>= 1) {
        if (threadIdx.x < s) red[threadIdx.x] += red[threadIdx.x + s];
        __syncthreads();
    }
    if (threadIdx.x == 0) partial[blockIdx.x] = red[0];
}

__global__ __launch_bounds__(256) void k_loss_fin(const double* __restrict__ partial, float* __restrict__ out_loss) {
    __shared__ double red[256];
    double s = 0.0;
    for (int i = threadIdx.x; i < 4096; i += 256) s += partial[i];
    red[threadIdx.x] = s;
    __syncthreads();
    for (int st = 128; st > 0; st >>= 1) {
        if (threadIdx.x < st) red[threadIdx.x] += red[threadIdx.x + st];
        __syncthreads();
    }
    if (threadIdx.x == 0)
        out_loss[0] = (float)(1.25 * red[0] / 1048576.0);
}

// -------- K7: conv 3x3 p1, 8->64. 4 oh x 8 co per thread; bf16 output.
__global__ __launch_bounds__(256) void k_dec1(const float* __restrict__ zq, const float* __restrict__ w,
                                              const float* __restrict__ bias, ushort* __restrict__ out) {
    int t = blockIdx.x * 256 + threadIdx.x;
    int ow  = t & 63;
    int oh0 = ((t >> 6) & 15) * 4;
    int co0 = rfl((t >> 10) & 7) * 8;
    int b   = rfl(t >> 13);
    float acc[4][8] = {};
    for (int ci = 0; ci < 8; ci++) {
        const float* ip = zq + (b * 8 + ci) * 4096;
        const float* wp = w + (co0 * 8 + ci) * 9;      // co stride 72
        #pragma unroll
        for (int r = 0; r < 6; r++) {
            int ih = oh0 - 1 + r;
            bool rok = (ih >= 0) && (ih < 64);
            int ihc = rok ? ih : 0;
            float v[3];
            #pragma unroll
            for (int c = 0; c < 3; c++) {
                int iw = ow - 1 + c;
                bool ok = rok && (iw >= 0) && (iw < 64);
                int iwc = iw < 0 ? 0 : (iw > 63 ? 63 : iw);
                float vv = ip[ihc * 64 + iwc];
                v[c] = ok ? vv : 0.f;
            }
            #pragma unroll
            for (int o = 0; o < 4; o++) {
                int kh = r - o;
                if (kh >= 0 && kh < 3) {
                    #pragma unroll
                    for (int cc = 0; cc < 8; cc++) {
                        const float* wc = wp + cc * 72 + kh * 3;
                        acc[o][cc] = __builtin_fmaf(v[0], wc[0], acc[o][cc]);
                        acc[o][cc] = __builtin_fmaf(v[1], wc[1], acc[o][cc]);
                        acc[o][cc] = __builtin_fmaf(v[2], wc[2], acc[o][cc]);
                    }
                }
            }
        }
    }
    #pragma unroll
    for (int cc = 0; cc < 8; cc++) {
        float bv = bias[co0 + cc];
        #pragma unroll
        for (int o = 0; o < 4; o++) {
            float v = acc[o][cc] + bv;
            out[((b * 64 + co0 + cc) * 64 + oh0 + o) * 64 + ow] = f2bf(v > 0.f ? v : 0.f);
        }
    }
}

// -------- Weight prep for MFMA dect (unchanged).
template <int CI, int CO>
__global__ __launch_bounds__(256) void k_wprep(const float* __restrict__ w, ushort* __restrict__ Wf) {
    constexpr int NT = CO / 16;
    int t = blockIdx.x * 256 + threadIdx.x;
    if (t >= 4 * NT * 8 * 64) return;
    int lane = t & 63;
    int kt = (t >> 6) & 7;
    int nt = (t >> 9) % NT;
    int q  = t / (512 * NT);
    int py = q >> 1, px = q & 1;
    int n = nt * 16 + (lane & 15);
    int cb = (kt & 1) * 32 + (lane >> 4) * 8;
    int tap = kt >> 1, dy = tap >> 1, dx = tap & 1;
    #pragma unroll
    for (int jj = 0; jj < 8; jj++) {
        int ci = cb + jj;
        float v = w[((n * CI + ci) * 4 + (py + 2 * dy)) * 4 + (px + 2 * dx)];
        Wf[(((q * NT + nt) * 8 + kt) * 64 + lane) * 8 + jj] = f2bf(v);
    }
}

// -------- K8/K9: transposed conv via bf16 MFMA. 8x16 input tile, bf16 in/out.
template <int CI, int CO, int HIN>
__global__ __launch_bounds__(256) void k_dect_mfma(const ushort* __restrict__ in, const ushort* __restrict__ Wf,
                                                   const float* __restrict__ bias, ushort* __restrict__ out) {
    constexpr int NT = CO / 16;
    constexpr int TX = HIN / 16;
    constexpr int TY = HIN / 8;
    constexpr int HOUT = 2 * HIN;
    __shared__ alignas(16) ushort L[10 * 18 * 72];   // 25,920 B -> 6 blocks/CU
    int blk = blockIdx.x;
    int b = blk / (TY * TX);
    int tile = blk - b * (TY * TX);
    int tyy = tile / TX, txx = tile - tyy * TX;
    int i0 = tyy * 8, j0 = txx * 16;
    const ushort* ip = in + (size_t)b * CI * HIN * HIN;
    for (int e = threadIdx.x; e < 10 * 18 * CI; e += 256) {
        int ci = e / 180; int rem = e - ci * 180;
        int row = rem / 18; int col = rem - row * 18;
        int ih = i0 - 1 + row, iw = j0 - 1 + col;
        ushort v = 0;
        if (ih >= 0 && ih < HIN && iw >= 0 && iw < HIN)
            v = ip[(size_t)ci * (HIN * HIN) + ih * HIN + iw];
        L[(row * 18 + col) * 72 + ci] = v;
    }
    __syncthreads();
    int wv = threadIdx.x >> 6;          // wave = quadrant
    int lane = threadIdx.x & 63;
    int py = wv >> 1, px = wv & 1;
    int m = lane & 15, quad = lane >> 4;
    const ushort* wq = Wf + (size_t)wv * NT * 8 * 64 * 8;
    for (int il = 0; il < 8; il++) {
        s8v a[8];
        #pragma unroll
        for (int kt = 0; kt < 8; kt++) {
            int tap = kt >> 1, dy = tap >> 1, dx = tap & 1;
            int r = il + py + dy, cl = m + px + dx;
            a[kt] = *(s8v*)&L[(r * 18 + cl) * 72 + (kt & 1) * 32 + quad * 8];
        }
        #pragma unroll
        for (int nt = 0; nt < NT; nt++) {
            f4v acc = {0.f, 0.f, 0.f, 0.f};
            #pragma unroll
            for (int kt = 0; kt < 8; kt++) {
                s8v bf = *(const s8v*)&wq[((nt * 8 + kt) * 64 + lane) * 8];
                acc = __builtin_amdgcn_mfma_f32_16x16x32_bf16(a[kt], bf, acc, 0, 0, 0);
            }
            int co = nt * 16 + m;
            float bv = bias[co];
            int y = 2 * (i0 + il) + py;
            #pragma unroll
            for (int reg = 0; reg < 4; reg++) {
                int jD = j0 + quad * 4 + reg;
                int xx = 2 * jD + px;
                float v = acc[reg] + bv;
                out[((size_t)(b * CO + co) * HOUT + y) * HOUT + xx] = f2bf(v > 0.f ? v : 0.f);
            }
        }
    }
}

// -------- K10: conv 3x3 p1, 32->3, sigmoid. bf16 input, 4 y x 3 co per thread.
__global__ __launch_bounds__(256) void k_dec2(const ushort* __restrict__ in, const float* __restrict__ w,
                                              const float* __restrict__ bias, float* __restrict__ out) {
    int t = blockIdx.x * 256 + threadIdx.x;
    int x  = t & 255;
    int y0 = ((t >> 8) & 63) * 4;
    int b  = rfl(t >> 14);
    float acc[4][3] = {};
    for (int ci = 0; ci < 32; ci++) {
        const ushort* ip = in + (size_t)(b * 32 + ci) * 65536;
        const float* wp = w + ci * 9;            // co stride 288
        #pragma unroll
        for (int rr = 0; rr < 6; rr++) {
            int ih = y0 - 1 + rr;
            bool rok = (ih >= 0) && (ih < 256);
            int ihc = rok ? ih : 0;
            float v[3];
            #pragma unroll
            for (int c = 0; c < 3; c++) {
                int iw = x - 1 + c;
                bool ok = rok && (iw >= 0) && (iw < 256);
                int iwc = iw < 0 ? 0 : (iw > 255 ? 255 : iw);
                float vv = bf2f(ip[ihc * 256 + iwc]);
                v[c] = ok ? vv : 0.f;
            }
            #pragma unroll
            for (int o = 0; o < 4; o++) {
                int kh = rr - o;
                if (kh >= 0 && kh < 3) {
                    #pragma unroll
                    for (int co = 0; co < 3; co++) {
                        const float* wc = wp + co * 288 + kh * 3;
                        acc[o][co] = __builtin_fmaf(v[0], wc[0], acc[o][co]);
                        acc[o][co] = __builtin_fmaf(v[1], wc[1], acc[o][co]);
                        acc[o][co] = __builtin_fmaf(v[2], wc[2], acc[o][co]);
                    }
                }
            }
        }
    }
    #pragma unroll
    for (int co = 0; co < 3; co++) {
        float bv = bias[co];
        #pragma unroll
        for (int o = 0; o < 4; o++) {
            float v = acc[o][co] + bv;
            out[((size_t)(b * 3 + co) * 256 + y0 + o) * 256 + x] = 1.0f / (1.0f + expf(-v));
        }
    }
}

extern "C" void kernel_launch(void* const* d_in, const int* in_sizes, int n_in,
                              void* d_out, int out_size, void* d_ws, size_t ws_size,
                              hipStream_t stream) {
    const float* x    = (const float*)d_in[0];
    const float* ew1  = (const float*)d_in[1];
    const float* eb1  = (const float*)d_in[2];
    const float* ew2  = (const float*)d_in[3];
    const float* eb2  = (const float*)d_in[4];
    const float* ew3  = (const float*)d_in[5];
    const float* eb3  = (const float*)d_in[6];
    const float* cb   = (const float*)d_in[7];
    const float* dw1  = (const float*)d_in[8];
    const float* db1  = (const float*)d_in[9];
    const float* dtw1 = (const float*)d_in[10];
    const float* dtb1 = (const float*)d_in[11];
    const float* dtw2 = (const float*)d_in[12];
    const float* dtb2 = (const float*)d_in[13];
    const float* dw2  = (const float*)d_in[14];
    const float* db2  = (const float*)d_in[15];

    char* ws = (char*)d_ws;
    float*  z32  = (float*) (ws);               //  4,194,304 B
    float*  zq   = (float*) (ws + 4194304);     //  4,194,304 B
    int*    idx  = (int*)   (ws + 8388608);     //    524,288 B
    double* part = (double*)(ws + 8912896);     //     32,768 B
    ushort* Wf1  = (ushort*)(ws + 8945664);     //    131,072 B
    ushort* Wf2  = (ushort*)(ws + 9076736);     //     65,536 B
    char* region = ws + 9142272;

    size_t fixed = 9142272;
    size_t avail = (ws_size > fixed) ? ws_size - fixed : 0;
    int ce = 32, cd = 32;
    while (ce > 1 && (size_t)ce * 3145728ull > avail) ce >>= 1;   // h1(2MB)+h2(1MB) fp32
    while (cd > 1 && (size_t)cd * 6815744ull > avail) cd >>= 1;   // d3(.5)+d4(2)+d5(4MB) bf16

    float*  h1c = (float*)region;                                 // (ce,32,128,128) fp32
    float*  h2c = (float*)(region + (size_t)ce * 2097152ull);     // (ce,64,64,64) fp32
    ushort* d3c = (ushort*)region;                                // (cd,64,64,64) bf16
    ushort* d4c = (ushort*)(region + (size_t)cd * 524288ull);     // (cd,64,128,128) bf16
    ushort* d5c = (ushort*)(region + (size_t)cd * 2621440ull);    // (cd,32,256,256) bf16

    float* out      = (float*)d_out;
    float* out_loss = out + 6291456;
    float* out_idx  = out + 6291457;

    for (int c = 0; c < 32 / ce; c++) {
        const float* xc = x + (size_t)c * ce * 196608ull;
        k_conv1<<<ce * 64, 256, 0, stream>>>(xc, ew1, eb1, h1c);
        k_conv2t<<<ce * 64, 256, 0, stream>>>(h1c, ew2, eb2, h2c);
        k_conv3<<<ce * 16,  256, 0, stream>>>(h2c, ew3, eb3, z32 + (size_t)c * ce * 32768ull);
    }

    k_vq<<<512, 256, 0, stream>>>(z32, cb, idx, out_idx);
    k_zq<<<4096, 256, 0, stream>>>(idx, cb, z32, zq, part);
    k_loss_fin<<<1, 256, 0, stream>>>(part, out_loss);

    k_wprep<64, 64><<<32, 256, 0, stream>>>(dtw1, Wf1);
    k_wprep<64, 32><<<16, 256, 0, stream>>>(dtw2, Wf2);

    for (int c = 0; c < 32 / cd; c++) {
        const float* zqc = zq + (size_t)c * cd * 32768ull;
        float* outc = out + (size_t)c * cd * 196608ull;
        k_dec1<<<cd * 32, 256, 0, stream>>>(zqc, dw1, db1, d3c);
        k_dect_mfma<64, 64, 64 ><<<cd * 32, 256, 0, stream>>>(d3c, Wf1, dtb1, d4c);
        k_dect_mfma<64, 32, 128><<<cd * 128, 256, 0, stream>>>(d4c, Wf2, dtb2, d5c);
        k_dec2<<<cd * 64, 256, 0, stream>>>(d5c, dw2, db2, outc);
    }
}